// Round 3
// baseline (187.046 us; speedup 1.0000x reference)
//
#include <hip/hip_runtime.h>

#define NVAL 15
#define TPB  256
#define VPT  4   // float4 per tile per thread
#define NT   4   // tiles per block, 2-deep software pipeline (A/B buffers)

typedef float fvec4 __attribute__((ext_vector_type(4)));

__device__ __forceinline__ fvec4 quant4(fvec4 v, const float* tf, float sc1, float k)
{
    float xs0 = v.x * sc1, xs1 = v.y * sc1, xs2 = v.z * sc1, xs3 = v.w * sc1;
    int c0 = 0, c1 = 0, c2 = 0, c3 = 0;
#pragma unroll
    for (int i = 0; i < NVAL; ++i) {
        float t = tf[i];
        c0 += (xs0 > t);   // strict > : searchsorted side="left"
        c1 += (xs1 > t);
        c2 += (xs2 > t);
        c3 += (xs3 > t);
    }
    fvec4 r;
    r.x = k * (float)c0;
    r.y = k * (float)c1;
    r.z = k * (float)c2;
    r.w = k * (float)c3;
    return r;
}

// R7: software-pipelined main kernel. R6 proved the single-shot structure
// leaves the HBM read queue bursty (R5 counters: 2.3 TB/s, VALUBusy 31%,
// occupancy 50% — nothing saturated). Each block now owns 4 contiguous tiles
// (64 KB) and runs a 2-deep pipeline: store tile i while issuing tile i+2's
// NT loads into the freed registers. Every wave keeps reads in flight during
// compute -> sustained queue depth, fill-kernel-like demand smoothness.
// Register budget: 32 data + 15 tf + addr/temps ~ 60 <= 64 VGPR (8 waves/SIMD).
// Grid 1568 blocks x 4 waves = 6272 waves -> entire grid co-resident.
__global__ __launch_bounds__(TPB) void ltq_main(
    const float* __restrict__ x,
    const float* __restrict__ start,
    const float* __restrict__ a,
    const float* __restrict__ scale1,
    const float* __restrict__ scale2,
    float* __restrict__ out)
{
    const int tile_f4 = TPB * VPT;                        // 1024 float4 per tile
    const long long base = (long long)blockIdx.x * (tile_f4 * NT) + threadIdx.x;
    const fvec4* __restrict__ x4 = (const fvec4*)x + base;
    fvec4* __restrict__ o4 = (fvec4*)out + base;

    fvec4 A[VPT], B[VPT];
    // prologue: tiles 0 and 1 in flight (8 KB/wave outstanding)
#pragma unroll
    for (int j = 0; j < VPT; ++j)
        A[j] = __builtin_nontemporal_load(&x4[j * TPB]);
#pragma unroll
    for (int j = 0; j < VPT; ++j)
        B[j] = __builtin_nontemporal_load(&x4[tile_f4 + j * TPB]);
    __builtin_amdgcn_sched_barrier(0);  // pin: prologue loads issued before any compute

    // threshold setup overlaps the in-flight loads
    const float s   = start[0];
    const float sc1 = scale1[0];
    const float k   = (float)(2.0 / 15.0) * scale2[0];
    float tf[NVAL];
    float cum = 0.0f;
#pragma unroll
    for (int i = 0; i < NVAL; ++i) {
        float ai = a[i];
        float ap = (ai > 1e-3f) ? ai : 1e-3f;   // jnp.where(a > EPS, a, EPS)
        tf[i] = (s + cum) + 0.5f * ap;          // tb[i] + a_pos[i]/2, exact fp32 association
        cum += ap;                              // sequential cumsum, matches np
    }

    // steady state: store tile i, refill same regs with tile i+2
#pragma unroll
    for (int j = 0; j < VPT; ++j) {
        fvec4 r = quant4(A[j], tf, sc1, k);
        o4[j * TPB] = r;
        A[j] = __builtin_nontemporal_load(&x4[2 * tile_f4 + j * TPB]);
    }
    __builtin_amdgcn_sched_barrier(0);
#pragma unroll
    for (int j = 0; j < VPT; ++j) {
        fvec4 r = quant4(B[j], tf, sc1, k);
        o4[tile_f4 + j * TPB] = r;
        B[j] = __builtin_nontemporal_load(&x4[3 * tile_f4 + j * TPB]);
    }
    __builtin_amdgcn_sched_barrier(0);

    // epilogue: drain tiles 2 and 3
#pragma unroll
    for (int j = 0; j < VPT; ++j)
        o4[2 * tile_f4 + j * TPB] = quant4(A[j], tf, sc1, k);
#pragma unroll
    for (int j = 0; j < VPT; ++j)
        o4[3 * tile_f4 + j * TPB] = quant4(B[j], tf, sc1, k);
}

// Generic tail (not launched when the main grid tiles n exactly — true here).
__global__ __launch_bounds__(TPB) void ltq_tail(
    const float* __restrict__ x,
    const float* __restrict__ start,
    const float* __restrict__ a,
    const float* __restrict__ scale1,
    const float* __restrict__ scale2,
    float* __restrict__ out,
    long long f4_done, long long n4, long long n)
{
    const float s   = start[0];
    const float sc1 = scale1[0];
    const float k   = (float)(2.0 / 15.0) * scale2[0];
    float tf[NVAL];
    float cum = 0.0f;
#pragma unroll
    for (int i = 0; i < NVAL; ++i) {
        float ai = a[i];
        float ap = (ai > 1e-3f) ? ai : 1e-3f;
        tf[i] = (s + cum) + 0.5f * ap;
        cum += ap;
    }

    const long long stride = (long long)gridDim.x * blockDim.x;
    const fvec4* __restrict__ x4 = (const fvec4*)x;
    fvec4* __restrict__ o4 = (fvec4*)out;
    for (long long i = f4_done + blockIdx.x * (long long)blockDim.x + threadIdx.x;
         i < n4; i += stride) {
        o4[i] = quant4(x4[i], tf, sc1, k);
    }
    for (long long i = (n4 << 2) + blockIdx.x * (long long)blockDim.x + threadIdx.x;
         i < n; i += stride) {
        float xs = x[i] * sc1;
        int c = 0;
#pragma unroll
        for (int t = 0; t < NVAL; ++t) c += (xs > tf[t]);
        out[i] = k * (float)c;
    }
}

extern "C" void kernel_launch(void* const* d_in, const int* in_sizes, int n_in,
                              void* d_out, int out_size, void* d_ws, size_t ws_size,
                              hipStream_t stream) {
    const float* x      = (const float*)d_in[0];
    const float* start  = (const float*)d_in[1];
    const float* a      = (const float*)d_in[2];
    const float* scale1 = (const float*)d_in[3];
    const float* scale2 = (const float*)d_in[4];
    float* out = (float*)d_out;

    const long long n  = in_sizes[0];
    const long long n4 = n >> 2;
    const long long per_block = (long long)TPB * VPT * NT; // float4s per block
    const long long blocks = n4 / per_block;               // exact-fit main grid

    if (blocks > 0) {
        // N=25,690,112 -> n4=6,422,528 -> 1568 blocks, zero remainder.
        ltq_main<<<(int)blocks, TPB, 0, stream>>>(x, start, a, scale1, scale2, out);
    }
    const long long f4_done = blocks * per_block;
    if (f4_done < n4 || (n & 3)) {
        ltq_tail<<<512, TPB, 0, stream>>>(x, start, a, scale1, scale2, out,
                                          f4_done, n4, n);
    }
}

// Round 4
// 182.816 us; speedup vs baseline: 1.0231x; 1.0231x over previous
//
#include <hip/hip_runtime.h>

#define NVAL 15
#define TPB  256

typedef float fvec4 __attribute__((ext_vector_type(4)));

__device__ __forceinline__ fvec4 quant4(fvec4 v, const float* tf, float sc1, float k)
{
    float xs0 = v.x * sc1, xs1 = v.y * sc1, xs2 = v.z * sc1, xs3 = v.w * sc1;
    int c0 = 0, c1 = 0, c2 = 0, c3 = 0;
#pragma unroll
    for (int i = 0; i < NVAL; ++i) {
        float t = tf[i];
        c0 += (xs0 > t);   // strict > : searchsorted side="left"
        c1 += (xs1 > t);
        c2 += (xs2 > t);
        c3 += (xs3 > t);
    }
    fvec4 r;
    r.x = k * (float)c0;
    r.y = k * (float)c1;
    r.z = k * (float)c2;
    r.w = k * (float)c3;
    return r;
}

// R8: m13-replica looping kernel. R7's pinned register-pipeline FAILED (+9 µs:
// VGPR pressure + vmcnt entanglement from interleaved store/load under
// sched_barrier). This is the structure that actually measured 6.29 TB/s on
// this chip: a countable per-wave loop, gentle 2-way unroll, NO sched_barrier
// (compiler schedules next iteration's loads under current stores itself),
// NT loads kept (A/B-proven twice). Grid 1792 = 7 blocks/CU, fully
// co-resident, 28 waves/CU, each thread does exactly niter(=14) float4s.
// Register budget: 8 data + 15 tf + addr ~ 45 VGPR -> 8 waves/SIMD.
__global__ __launch_bounds__(TPB) void ltq_main(
    const float* __restrict__ x,
    const float* __restrict__ start,
    const float* __restrict__ a,
    const float* __restrict__ scale1,
    const float* __restrict__ scale2,
    float* __restrict__ out,
    int niter)
{
    const long long tid = (long long)blockIdx.x * TPB + threadIdx.x;
    const long long S   = (long long)gridDim.x * TPB;    // stride in float4s
    const fvec4* __restrict__ x4 = (const fvec4*)x + tid;
    fvec4* __restrict__ o4 = (fvec4*)out + tid;

    // threshold setup (uniform -> scalar loads), amortized over niter iterations
    const float s   = start[0];
    const float sc1 = scale1[0];
    const float k   = (float)(2.0 / 15.0) * scale2[0];
    float tf[NVAL];
    float cum = 0.0f;
#pragma unroll
    for (int i = 0; i < NVAL; ++i) {
        float ai = a[i];
        float ap = (ai > 1e-3f) ? ai : 1e-3f;   // jnp.where(a > EPS, a, EPS)
        tf[i] = (s + cum) + 0.5f * ap;          // tb[i] + a_pos[i]/2, exact fp32 association
        cum += ap;                              // sequential cumsum, matches np
    }

    long long off = 0;
    int j = 0;
    for (; j + 2 <= niter; j += 2) {
        fvec4 v0 = __builtin_nontemporal_load(&x4[off]);      // x never re-read:
        fvec4 v1 = __builtin_nontemporal_load(&x4[off + S]);  // keep LLC for writes
        o4[off]     = quant4(v0, tf, sc1, k);
        o4[off + S] = quant4(v1, tf, sc1, k);
        off += 2 * S;
    }
    if (j < niter) {
        fvec4 v0 = __builtin_nontemporal_load(&x4[off]);
        o4[off] = quant4(v0, tf, sc1, k);
    }
}

// Generic tail (not launched when niter*threads == n4 and n%4==0 — true here).
__global__ __launch_bounds__(TPB) void ltq_tail(
    const float* __restrict__ x,
    const float* __restrict__ start,
    const float* __restrict__ a,
    const float* __restrict__ scale1,
    const float* __restrict__ scale2,
    float* __restrict__ out,
    long long f4_done, long long n4, long long n)
{
    const float s   = start[0];
    const float sc1 = scale1[0];
    const float k   = (float)(2.0 / 15.0) * scale2[0];
    float tf[NVAL];
    float cum = 0.0f;
#pragma unroll
    for (int i = 0; i < NVAL; ++i) {
        float ai = a[i];
        float ap = (ai > 1e-3f) ? ai : 1e-3f;
        tf[i] = (s + cum) + 0.5f * ap;
        cum += ap;
    }

    const long long stride = (long long)gridDim.x * blockDim.x;
    const fvec4* __restrict__ x4 = (const fvec4*)x;
    fvec4* __restrict__ o4 = (fvec4*)out;
    for (long long i = f4_done + blockIdx.x * (long long)blockDim.x + threadIdx.x;
         i < n4; i += stride) {
        o4[i] = quant4(x4[i], tf, sc1, k);
    }
    for (long long i = (n4 << 2) + blockIdx.x * (long long)blockDim.x + threadIdx.x;
         i < n; i += stride) {
        float xs = x[i] * sc1;
        int c = 0;
#pragma unroll
        for (int t = 0; t < NVAL; ++t) c += (xs > tf[t]);
        out[i] = k * (float)c;
    }
}

extern "C" void kernel_launch(void* const* d_in, const int* in_sizes, int n_in,
                              void* d_out, int out_size, void* d_ws, size_t ws_size,
                              hipStream_t stream) {
    const float* x      = (const float*)d_in[0];
    const float* start  = (const float*)d_in[1];
    const float* a      = (const float*)d_in[2];
    const float* scale1 = (const float*)d_in[3];
    const float* scale2 = (const float*)d_in[4];
    float* out = (float*)d_out;

    const long long n  = in_sizes[0];
    const long long n4 = n >> 2;

    const int  blocks   = 1792;                            // 7 blocks/CU x 256 CU
    const long long thr = (long long)blocks * TPB;         // 458,752 threads
    const long long niter = n4 / thr;                      // N=25,690,112 -> 14 exact

    if (niter > 0) {
        ltq_main<<<blocks, TPB, 0, stream>>>(x, start, a, scale1, scale2, out,
                                             (int)niter);
    }
    const long long f4_done = niter * thr;
    if (f4_done < n4 || (n & 3)) {
        ltq_tail<<<512, TPB, 0, stream>>>(x, start, a, scale1, scale2, out,
                                          f4_done, n4, n);
    }
}

// Round 5
// 180.876 us; speedup vs baseline: 1.0341x; 1.0107x over previous
//
#include <hip/hip_runtime.h>

#define NVAL 15
#define TPB  256
#define VPT  4   // float4 loads per thread — R6-proven best burst depth

typedef float fvec4 __attribute__((ext_vector_type(4)));

__device__ __forceinline__ fvec4 quant4(fvec4 v, const float* tf, float sc1, float k)
{
    float xs0 = v.x * sc1, xs1 = v.y * sc1, xs2 = v.z * sc1, xs3 = v.w * sc1;
    int c0 = 0, c1 = 0, c2 = 0, c3 = 0;
#pragma unroll
    for (int i = 0; i < NVAL; ++i) {
        float t = tf[i];
        c0 += (xs0 > t);   // strict > : searchsorted side="left"
        c1 += (xs1 > t);
        c2 += (xs2 > t);
        c3 += (xs3 > t);
    }
    fvec4 r;
    r.x = k * (float)c0;
    r.y = k * (float)c1;
    r.z = k * (float)c2;
    r.w = k * (float)c3;
    return r;
}

// R9 = R6 (best: 178.1 µs total) with ONE variable flipped: NT stores.
// Structural ladder is closed — single-shot exact-fit beat manual pipelining
// (R7, +9 µs) and persistent grid-stride (R8, +5 µs); HW block-generation
// pipelining wins. Store policy is the only never-tested memory knob.
// Stream model: the harness fill sustains 6.6 TB/s write-through, so LLC
// write absorption may be a myth here; NT stores take the same
// fire-and-forget path. Absorb model predicts regression -> revert.
__global__ __launch_bounds__(TPB) void ltq_main(
    const float* __restrict__ x,
    const float* __restrict__ start,
    const float* __restrict__ a,
    const float* __restrict__ scale1,
    const float* __restrict__ scale2,
    float* __restrict__ out)
{
    const long long base = (long long)blockIdx.x * (TPB * VPT) + threadIdx.x;
    const fvec4* __restrict__ x4 = (const fvec4*)x + base;
    fvec4* __restrict__ o4 = (fvec4*)out + base;

    fvec4 v[VPT];
#pragma unroll
    for (int j = 0; j < VPT; ++j)
        v[j] = __builtin_nontemporal_load(&x4[j * TPB]);  // NT loads: A/B-proven twice

    __builtin_amdgcn_sched_barrier(0);  // pin: all loads issued before any compute

    // threshold setup overlaps the in-flight loads
    const float s   = start[0];
    const float sc1 = scale1[0];
    const float k   = (float)(2.0 / 15.0) * scale2[0];
    float tf[NVAL];
    float cum = 0.0f;
#pragma unroll
    for (int i = 0; i < NVAL; ++i) {
        float ai = a[i];
        float ap = (ai > 1e-3f) ? ai : 1e-3f;   // jnp.where(a > EPS, a, EPS)
        tf[i] = (s + cum) + 0.5f * ap;          // tb[i] + a_pos[i]/2, exact fp32 association
        cum += ap;                              // sequential cumsum, matches np
    }

#pragma unroll
    for (int j = 0; j < VPT; ++j) {
        fvec4 r = quant4(v[j], tf, sc1, k);
        __builtin_nontemporal_store(r, &o4[j * TPB]);    // R9 single variable: NT store
    }
}

// Generic tail (not launched when the main grid tiles n exactly — true here).
__global__ __launch_bounds__(TPB) void ltq_tail(
    const float* __restrict__ x,
    const float* __restrict__ start,
    const float* __restrict__ a,
    const float* __restrict__ scale1,
    const float* __restrict__ scale2,
    float* __restrict__ out,
    long long f4_done, long long n4, long long n)
{
    const float s   = start[0];
    const float sc1 = scale1[0];
    const float k   = (float)(2.0 / 15.0) * scale2[0];
    float tf[NVAL];
    float cum = 0.0f;
#pragma unroll
    for (int i = 0; i < NVAL; ++i) {
        float ai = a[i];
        float ap = (ai > 1e-3f) ? ai : 1e-3f;
        tf[i] = (s + cum) + 0.5f * ap;
        cum += ap;
    }

    const long long stride = (long long)gridDim.x * blockDim.x;
    const fvec4* __restrict__ x4 = (const fvec4*)x;
    fvec4* __restrict__ o4 = (fvec4*)out;
    for (long long i = f4_done + blockIdx.x * (long long)blockDim.x + threadIdx.x;
         i < n4; i += stride) {
        o4[i] = quant4(x4[i], tf, sc1, k);
    }
    for (long long i = (n4 << 2) + blockIdx.x * (long long)blockDim.x + threadIdx.x;
         i < n; i += stride) {
        float xs = x[i] * sc1;
        int c = 0;
#pragma unroll
        for (int t = 0; t < NVAL; ++t) c += (xs > tf[t]);
        out[i] = k * (float)c;
    }
}

extern "C" void kernel_launch(void* const* d_in, const int* in_sizes, int n_in,
                              void* d_out, int out_size, void* d_ws, size_t ws_size,
                              hipStream_t stream) {
    const float* x      = (const float*)d_in[0];
    const float* start  = (const float*)d_in[1];
    const float* a      = (const float*)d_in[2];
    const float* scale1 = (const float*)d_in[3];
    const float* scale2 = (const float*)d_in[4];
    float* out = (float*)d_out;

    const long long n  = in_sizes[0];
    const long long n4 = n >> 2;
    const long long per_block = (long long)TPB * VPT;      // float4s per block
    const long long blocks = n4 / per_block;               // exact-fit main grid

    if (blocks > 0) {
        // N=25,690,112 -> n4=6,422,528 -> 6272 blocks, zero remainder.
        ltq_main<<<(int)blocks, TPB, 0, stream>>>(x, start, a, scale1, scale2, out);
    }
    const long long f4_done = blocks * per_block;
    if (f4_done < n4 || (n & 3)) {
        ltq_tail<<<512, TPB, 0, stream>>>(x, start, a, scale1, scale2, out,
                                          f4_done, n4, n);
    }
}